// Round 2
// baseline (209.976 us; speedup 1.0000x reference)
//
#include <hip/hip_runtime.h>

#define BB   8
#define CC   64
#define HWN  19200
#define NPTS 12800
#define NSUB 3200
#define KNN  16
#define OUTN (HWN + NSUB)   // 22400

typedef __attribute__((ext_vector_type(8))) short short8;
typedef __attribute__((ext_vector_type(4))) float floatx4;

__device__ __forceinline__ unsigned short f2bf(float f) {
    union { float f; unsigned int i; } v; v.f = f;
    unsigned int r = v.i + 0x7fffu + ((v.i >> 16) & 1u);
    return (unsigned short)(r >> 16);
}
__device__ __forceinline__ float bf2f(unsigned short u) {
    union { unsigned int i; float f; } v; v.i = ((unsigned int)u) << 16; return v.f;
}

// Convert the 4 weight matrices (f32) into one concatenated bf16 buffer.
// dst layout: [0:4096) w_p2r_pre, [4096:8192) w_r2p_pre,
//             [8192:16384) w_p2r_fuse, [16384:24576) w_r2p_fuse
__global__ void k_cvt_w(const float* __restrict__ a, const float* __restrict__ b,
                        const float* __restrict__ c, const float* __restrict__ d,
                        ushort* __restrict__ dst) {
    int i = blockIdx.x * 256 + threadIdx.x;   // 0..24575
    float v;
    if (i < 4096)       v = a[i];
    else if (i < 8192)  v = b[i - 4096];
    else if (i < 16384) v = c[i - 8192];
    else                v = d[i - 16384];
    dst[i] = f2bf(v);
}

// f32 [B][C][N] -> bf16 [B][N][C]
__global__ void k_transpose_cvt(const float* __restrict__ in, ushort* __restrict__ out, int N) {
    __shared__ ushort tile[64][65];
    int b  = blockIdx.y;
    int n0 = blockIdx.x * 64;
    int tx = threadIdx.x & 63;
    int ty = threadIdx.x >> 6;   // 0..3
    const float* src = in + (size_t)b * CC * N + n0;
    #pragma unroll
    for (int c = ty; c < CC; c += 4)
        tile[c][tx] = f2bf(src[(size_t)c * N + tx]);
    __syncthreads();
    ushort* dst = out + ((size_t)b * N + n0) * CC;
    #pragma unroll
    for (int n = ty; n < 64; n += 4)
        dst[(size_t)n * CC + tx] = tile[tx][n];
}

// xT bf16 [B][Nin][64]; idx [B][NSUB][16]; outT bf16 [B][NSUB][64] = max over K
__global__ void k_gather_maxpool(const ushort* __restrict__ xT, const int* __restrict__ idx,
                                 ushort* __restrict__ outT, int Nin) {
    int tid  = threadIdx.x;
    int c4   = (tid & 15) * 4;     // 4 channels per lane
    int mloc = tid >> 4;           // 16 points per block
    int b = blockIdx.y;
    int m = blockIdx.x * 16 + mloc;
    const int* ip = idx + ((size_t)b * NSUB + m) * KNN;
    const ushort* xb = xT + (size_t)b * Nin * CC + c4;
    float a0 = -1e30f, a1 = -1e30f, a2 = -1e30f, a3 = -1e30f;
    #pragma unroll
    for (int k = 0; k < KNN; ++k) {
        int j = ip[k];
        ushort4 v = *(const ushort4*)(xb + (size_t)j * CC);
        a0 = fmaxf(a0, bf2f(v.x));
        a1 = fmaxf(a1, bf2f(v.y));
        a2 = fmaxf(a2, bf2f(v.z));
        a3 = fmaxf(a3, bf2f(v.w));
    }
    ushort4 r;
    r.x = f2bf(a0); r.y = f2bf(a1); r.z = f2bf(a2); r.w = f2bf(a3);
    *(ushort4*)(outT + ((size_t)b * NSUB + m) * CC + c4) = r;
}

// outT[b][n][o] = relu(s[o]*(sum_k W[o][k]*xT[b][n][k]) + bias[o]); bf16 out.
// D = Xtile(A, rows=n) * W^T(B, cols=o); K=64.
__global__ void k_gemm_pre(const ushort* __restrict__ xT,   // bf16 [B][NSUB][64]
                           const ushort* __restrict__ W,    // bf16 [64][64]
                           const float* __restrict__ s,
                           const float* __restrict__ bias,
                           ushort* __restrict__ outT) {     // bf16 [B][NSUB][64]
    int wave = threadIdx.x >> 6;
    int lane = threadIdx.x & 63;
    int b    = blockIdx.y;
    int n0   = (blockIdx.x * 4 + wave) * 16;
    int l15  = lane & 15;
    int quad = lane >> 4;
    const ushort* xrow = xT + ((size_t)b * NSUB + n0 + l15) * CC + quad * 8;
    floatx4 acc[4] = {{0.f,0.f,0.f,0.f},{0.f,0.f,0.f,0.f},{0.f,0.f,0.f,0.f},{0.f,0.f,0.f,0.f}};
    #pragma unroll
    for (int kk = 0; kk < 2; ++kk) {
        short8 a = *(const short8*)(xrow + kk * 32);
        #pragma unroll
        for (int t = 0; t < 4; ++t) {
            short8 w = *(const short8*)(W + (size_t)(t * 16 + l15) * CC + kk * 32 + quad * 8);
            acc[t] = __builtin_amdgcn_mfma_f32_16x16x32_bf16(a, w, acc[t], 0, 0, 0);
        }
    }
    #pragma unroll
    for (int t = 0; t < 4; ++t) {
        int o = t * 16 + l15;                 // D col
        float sv = s[o], bv = bias[o];
        #pragma unroll
        for (int r = 0; r < 4; ++r) {
            int n = n0 + quad * 4 + r;        // D row
            float y = fmaxf(acc[t][r] * sv + bv, 0.f);
            outT[((size_t)b * NSUB + n) * CC + o] = f2bf(y);
        }
    }
}

// out[b][o][pos0+n] = relu(s[o]*(sum_{k<128} W[o][k]*X[k][n]) + bias[o]); f32 out.
// X rows: k<64 -> x1T[b][n][k]; k>=64 -> x2T[b][n2][k-64], n2 = idx2 ? idx2[b][n] : n
// D = W(A, rows=o) * Xtile(B, cols=n); K=128.
__global__ void k_gemm_fuse(const ushort* __restrict__ x1T,
                            const ushort* __restrict__ x2T,  // bf16 [B][NSUB][64]
                            const int* __restrict__ idx2,    // [B][N] or nullptr
                            const ushort* __restrict__ W,    // bf16 [64][128]
                            const float* __restrict__ s,
                            const float* __restrict__ bias,
                            float* __restrict__ out,         // d_out f32 [B][64][OUTN]
                            int N, int pos0) {
    int wave = threadIdx.x >> 6;
    int lane = threadIdx.x & 63;
    int b    = blockIdx.y;
    int n0   = (blockIdx.x * 4 + wave) * 16;
    int l15  = lane & 15;
    int quad = lane >> 4;
    int n    = n0 + l15;                      // B-operand column
    int n2   = idx2 ? idx2[(size_t)b * N + n] : n;
    const ushort* r1 = x1T + ((size_t)b * N + n) * CC + quad * 8;
    const ushort* r2 = x2T + ((size_t)b * NSUB + n2) * CC + quad * 8;
    floatx4 acc[4] = {{0.f,0.f,0.f,0.f},{0.f,0.f,0.f,0.f},{0.f,0.f,0.f,0.f},{0.f,0.f,0.f,0.f}};
    #pragma unroll
    for (int kk = 0; kk < 4; ++kk) {
        short8 xb = (kk < 2) ? *(const short8*)(r1 + kk * 32)
                             : *(const short8*)(r2 + (kk - 2) * 32);
        #pragma unroll
        for (int t = 0; t < 4; ++t) {
            short8 w = *(const short8*)(W + (size_t)(t * 16 + l15) * 128 + kk * 32 + quad * 8);
            acc[t] = __builtin_amdgcn_mfma_f32_16x16x32_bf16(w, xb, acc[t], 0, 0, 0);
        }
    }
    #pragma unroll
    for (int t = 0; t < 4; ++t) {
        #pragma unroll
        for (int r = 0; r < 4; ++r) {
            int o = t * 16 + quad * 4 + r;    // D row
            float y = fmaxf(acc[t][r] * s[o] + bias[o], 0.f);
            out[((size_t)b * CC + o) * OUTN + pos0 + n] = y;
        }
    }
}

extern "C" void kernel_launch(void* const* d_in, const int* in_sizes, int n_in,
                              void* d_out, int out_size, void* d_ws, size_t ws_size,
                              hipStream_t stream) {
    const float* rgb        = (const float*)d_in[0];
    const float* pfeat      = (const float*)d_in[1];
    const float* w_p2r_pre  = (const float*)d_in[2];
    const float* s_p2r_pre  = (const float*)d_in[3];
    const float* b_p2r_pre  = (const float*)d_in[4];
    const float* w_p2r_fuse = (const float*)d_in[5];
    const float* s_p2r_fuse = (const float*)d_in[6];
    const float* b_p2r_fuse = (const float*)d_in[7];
    const float* w_r2p_pre  = (const float*)d_in[8];
    const float* s_r2p_pre  = (const float*)d_in[9];
    const float* b_r2p_pre  = (const float*)d_in[10];
    const float* w_r2p_fuse = (const float*)d_in[11];
    const float* s_r2p_fuse = (const float*)d_in[12];
    const float* b_r2p_fuse = (const float*)d_in[13];
    const int*   pool_idx   = (const int*)d_in[14];
    const int*   p2r_idx    = (const int*)d_in[15];
    const int*   r2p_idx    = (const int*)d_in[16];
    float* out = (float*)d_out;

    char* ws = (char*)d_ws;
    ushort* wB    = (ushort*)ws; ws += 24576 * 2;                   // 48 KB
    ushort* pfT   = (ushort*)ws; ws += (size_t)BB * NPTS * CC * 2;  // 13.1 MB
    ushort* rgbT  = (ushort*)ws; ws += (size_t)BB * HWN  * CC * 2;  // 19.7 MB
    ushort* pe0T  = (ushort*)ws; ws += (size_t)BB * NSUB * CC * 2;  // 3.3 MB
    ushort* p2rT  = (ushort*)ws; ws += (size_t)BB * NSUB * CC * 2;
    ushort* r2pT0 = (ushort*)ws; ws += (size_t)BB * NSUB * CC * 2;
    ushort* r2pT  = (ushort*)ws; ws += (size_t)BB * NSUB * CC * 2;

    ushort* wP2Rp = wB;           // [64][64]
    ushort* wR2Pp = wB + 4096;    // [64][64]
    ushort* wP2Rf = wB + 8192;    // [64][128]
    ushort* wR2Pf = wB + 16384;   // [64][128]

    k_cvt_w<<<dim3(96), 256, 0, stream>>>(w_p2r_pre, w_r2p_pre, w_p2r_fuse, w_r2p_fuse, wB);

    k_transpose_cvt<<<dim3(NPTS / 64, BB), 256, 0, stream>>>(pfeat, pfT, NPTS);
    k_transpose_cvt<<<dim3(HWN  / 64, BB), 256, 0, stream>>>(rgb,   rgbT, HWN);

    k_gather_maxpool<<<dim3(NSUB / 16, BB), 256, 0, stream>>>(pfT,  pool_idx, pe0T,  NPTS);
    k_gather_maxpool<<<dim3(NSUB / 16, BB), 256, 0, stream>>>(rgbT, r2p_idx,  r2pT0, HWN);

    k_gemm_pre<<<dim3(NSUB / 64, BB), 256, 0, stream>>>(pe0T,  wP2Rp, s_p2r_pre, b_p2r_pre, p2rT);
    k_gemm_pre<<<dim3(NSUB / 64, BB), 256, 0, stream>>>(r2pT0, wR2Pp, s_r2p_pre, b_r2p_pre, r2pT);

    k_gemm_fuse<<<dim3(HWN / 64, BB), 256, 0, stream>>>(rgbT, p2rT, p2r_idx, wP2Rf,
                                                        s_p2r_fuse, b_p2r_fuse, out, HWN, 0);
    k_gemm_fuse<<<dim3(NSUB / 64, BB), 256, 0, stream>>>(pe0T, r2pT, nullptr, wR2Pf,
                                                         s_r2p_fuse, b_r2p_fuse, out, NSUB, HWN);
}

// Round 3
// 190.870 us; speedup vs baseline: 1.1001x; 1.1001x over previous
//
#include <hip/hip_runtime.h>

#define BB   8
#define CC   64
#define HWN  19200
#define NPTS 12800
#define NSUB 3200
#define KNN  16
#define OUTN (HWN + NSUB)   // 22400

typedef __attribute__((ext_vector_type(8))) short short8;
typedef __attribute__((ext_vector_type(4))) float floatx4;

__device__ __forceinline__ unsigned short f2bf(float f) {
    union { float f; unsigned int i; } v; v.f = f;
    unsigned int r = v.i + 0x7fffu + ((v.i >> 16) & 1u);
    return (unsigned short)(r >> 16);
}
__device__ __forceinline__ float bf2f(unsigned short u) {
    union { unsigned int i; float f; } v; v.i = ((unsigned int)u) << 16; return v.f;
}

// ---------------------------------------------------------------------------
// K1: both transposes (f32 [B][C][N] -> bf16 [B][N][C]) + weight conversion.
// grid (512, 8): x<200 pfeat, 200<=x<500 rgb, x>=500 weight cvt.
// ---------------------------------------------------------------------------
__global__ void k_prep(const float* __restrict__ pfeat, const float* __restrict__ rgb,
                       ushort* __restrict__ pfT, ushort* __restrict__ rgbT,
                       const float* __restrict__ wa, const float* __restrict__ wb,
                       const float* __restrict__ wc, const float* __restrict__ wd,
                       ushort* __restrict__ wB) {
    int x = blockIdx.x, b = blockIdx.y, tid = threadIdx.x;
    if (x >= 500) {
        int i = ((x - 500) * 8 + b) * 256 + tid;   // 0..24575
        float v;
        if (i < 4096)       v = wa[i];
        else if (i < 8192)  v = wb[i - 4096];
        else if (i < 16384) v = wc[i - 8192];
        else                v = wd[i - 16384];
        wB[i] = f2bf(v);
        return;
    }
    const float* in; ushort* out; int N, n0;
    if (x < 200) { in = pfeat; out = pfT;  N = NPTS; n0 = x * 64; }
    else         { in = rgb;   out = rgbT; N = HWN;  n0 = (x - 200) * 64; }
    __shared__ ushort tile[64][65];
    int tx = tid & 63;
    int ty = tid >> 6;   // 0..3
    const float* src = in + (size_t)b * CC * N + n0;
    #pragma unroll
    for (int c = ty; c < CC; c += 4)
        tile[c][tx] = f2bf(src[(size_t)c * N + tx]);
    __syncthreads();
    ushort* dst = out + ((size_t)b * N + n0) * CC;
    #pragma unroll
    for (int n = ty; n < 64; n += 4)
        dst[(size_t)n * CC + tx] = tile[tx][n];
}

// ---------------------------------------------------------------------------
// K2: gather + maxpool + pre-conv GEMM, fused. One block = 64 points.
// grid (100, 8): x<50 point-stream (pool_idx on pfT; writes pe0T + p2rT),
//                x>=50 rgb-stream (r2p_idx on rgbT; writes r2pT only).
// Maxpool result lives in LDS (padded to 72 ushorts/row for aligned short8
// reads with only 2-way bank aliasing), feeding MFMA A-fragments directly.
// ---------------------------------------------------------------------------
__global__ void k_gather_pre(const ushort* __restrict__ pfT, const ushort* __restrict__ rgbT,
                             const int* __restrict__ pool_idx, const int* __restrict__ r2p_idx,
                             const ushort* __restrict__ wB,
                             const float* __restrict__ s_p, const float* __restrict__ b_p,
                             const float* __restrict__ s_r, const float* __restrict__ b_r,
                             ushort* __restrict__ pe0T, ushort* __restrict__ p2rT,
                             ushort* __restrict__ r2pT) {
    __shared__ ushort sm[64][72];
    int x = blockIdx.x, b = blockIdx.y, tid = threadIdx.x;
    bool pt = (x < 50);
    int m0 = (pt ? x : x - 50) * 64;
    const ushort* xT  = pt ? pfT : rgbT;
    const int*    idx = pt ? pool_idx : r2p_idx;
    int Nin           = pt ? NPTS : HWN;
    const ushort* W   = pt ? wB : wB + 4096;       // [64][64]
    const float*  sv  = pt ? s_p : s_r;
    const float*  bv  = pt ? b_p : b_r;
    ushort*       dst = pt ? p2rT : r2pT;

    // ---- gather + maxpool: 16 points per pass, 16 lanes x 4ch per point ----
    int c4   = (tid & 15) * 4;
    int mloc = tid >> 4;          // 0..15
    const ushort* xb = xT + (size_t)b * Nin * CC + c4;
    #pragma unroll
    for (int pass = 0; pass < 4; ++pass) {
        int ml = mloc + pass * 16;
        int m  = m0 + ml;
        const int* ip = idx + ((size_t)b * NSUB + m) * KNN;
        float a0 = -1e30f, a1 = -1e30f, a2 = -1e30f, a3 = -1e30f;
        #pragma unroll
        for (int k = 0; k < KNN; ++k) {
            int j = ip[k];
            ushort4 v = *(const ushort4*)(xb + (size_t)j * CC);
            a0 = fmaxf(a0, bf2f(v.x));
            a1 = fmaxf(a1, bf2f(v.y));
            a2 = fmaxf(a2, bf2f(v.z));
            a3 = fmaxf(a3, bf2f(v.w));
        }
        ushort4 r;
        r.x = f2bf(a0); r.y = f2bf(a1); r.z = f2bf(a2); r.w = f2bf(a3);
        *(ushort4*)(&sm[ml][c4]) = r;
        if (pt)  // point-stream maxpool output is reused by the final fuse GEMM
            *(ushort4*)(pe0T + ((size_t)b * NSUB + m) * CC + c4) = r;
    }
    __syncthreads();

    // ---- pre-conv GEMM: D = Xtile(A rows=n from LDS) * W^T(B cols=o), K=64 ----
    int wave = tid >> 6;
    int lane = tid & 63;
    int l15  = lane & 15;
    int quad = lane >> 4;
    int nloc0 = wave * 16;
    floatx4 acc[4] = {{0.f,0.f,0.f,0.f},{0.f,0.f,0.f,0.f},{0.f,0.f,0.f,0.f},{0.f,0.f,0.f,0.f}};
    #pragma unroll
    for (int kk = 0; kk < 2; ++kk) {
        short8 a = *(const short8*)(&sm[nloc0 + l15][kk * 32 + quad * 8]);
        #pragma unroll
        for (int t = 0; t < 4; ++t) {
            short8 w = *(const short8*)(W + (size_t)(t * 16 + l15) * CC + kk * 32 + quad * 8);
            acc[t] = __builtin_amdgcn_mfma_f32_16x16x32_bf16(a, w, acc[t], 0, 0, 0);
        }
    }
    #pragma unroll
    for (int t = 0; t < 4; ++t) {
        int o = t * 16 + l15;                 // D col
        float ss = sv[o], bb = bv[o];
        #pragma unroll
        for (int r = 0; r < 4; ++r) {
            int n = m0 + nloc0 + quad * 4 + r;  // D row
            float y = fmaxf(acc[t][r] * ss + bb, 0.f);
            dst[((size_t)b * NSUB + n) * CC + o] = f2bf(y);
        }
    }
}

// ---------------------------------------------------------------------------
// K3: both fuse GEMMs. grid (350, 8): x<300 rgb-path (N=HWN, p2r gather),
// x>=300 point-path (N=NSUB, identity).  D = W(A rows=o) * X(B cols=n), K=128.
// ---------------------------------------------------------------------------
__global__ void k_fuse(const ushort* __restrict__ rgbT, const ushort* __restrict__ p2rT,
                       const ushort* __restrict__ pe0T, const ushort* __restrict__ r2pT,
                       const int* __restrict__ p2r_idx, const ushort* __restrict__ wB,
                       const float* __restrict__ s_p, const float* __restrict__ b_p,
                       const float* __restrict__ s_r, const float* __restrict__ b_r,
                       float* __restrict__ out) {
    int x = blockIdx.x, b = blockIdx.y;
    bool rp = (x < 300);
    const ushort* x1T = rp ? rgbT : pe0T;
    const ushort* x2T = rp ? p2rT : r2pT;
    int N             = rp ? HWN : NSUB;
    int pos0          = rp ? 0 : HWN;
    const ushort* W   = rp ? wB + 8192 : wB + 16384;   // [64][128]
    const float*  sv  = rp ? s_p : s_r;
    const float*  bv  = rp ? b_p : b_r;
    int x0            = rp ? x : x - 300;

    int wave = threadIdx.x >> 6;
    int lane = threadIdx.x & 63;
    int n0   = (x0 * 4 + wave) * 16;
    int l15  = lane & 15;
    int quad = lane >> 4;
    int n    = n0 + l15;
    int n2   = rp ? p2r_idx[(size_t)b * N + n] : n;
    const ushort* r1 = x1T + ((size_t)b * N + n) * CC + quad * 8;
    const ushort* r2 = x2T + ((size_t)b * NSUB + n2) * CC + quad * 8;
    floatx4 acc[4] = {{0.f,0.f,0.f,0.f},{0.f,0.f,0.f,0.f},{0.f,0.f,0.f,0.f},{0.f,0.f,0.f,0.f}};
    #pragma unroll
    for (int kk = 0; kk < 4; ++kk) {
        short8 xb = (kk < 2) ? *(const short8*)(r1 + kk * 32)
                             : *(const short8*)(r2 + (kk - 2) * 32);
        #pragma unroll
        for (int t = 0; t < 4; ++t) {
            short8 w = *(const short8*)(W + (size_t)(t * 16 + l15) * 128 + kk * 32 + quad * 8);
            acc[t] = __builtin_amdgcn_mfma_f32_16x16x32_bf16(w, xb, acc[t], 0, 0, 0);
        }
    }
    #pragma unroll
    for (int t = 0; t < 4; ++t) {
        #pragma unroll
        for (int r = 0; r < 4; ++r) {
            int o = t * 16 + quad * 4 + r;    // D row
            float y = fmaxf(acc[t][r] * sv[o] + bv[o], 0.f);
            out[((size_t)b * CC + o) * OUTN + pos0 + n] = y;
        }
    }
}

extern "C" void kernel_launch(void* const* d_in, const int* in_sizes, int n_in,
                              void* d_out, int out_size, void* d_ws, size_t ws_size,
                              hipStream_t stream) {
    const float* rgb        = (const float*)d_in[0];
    const float* pfeat      = (const float*)d_in[1];
    const float* w_p2r_pre  = (const float*)d_in[2];
    const float* s_p2r_pre  = (const float*)d_in[3];
    const float* b_p2r_pre  = (const float*)d_in[4];
    const float* w_p2r_fuse = (const float*)d_in[5];
    const float* s_p2r_fuse = (const float*)d_in[6];
    const float* b_p2r_fuse = (const float*)d_in[7];
    const float* w_r2p_pre  = (const float*)d_in[8];
    const float* s_r2p_pre  = (const float*)d_in[9];
    const float* b_r2p_pre  = (const float*)d_in[10];
    const float* w_r2p_fuse = (const float*)d_in[11];
    const float* s_r2p_fuse = (const float*)d_in[12];
    const float* b_r2p_fuse = (const float*)d_in[13];
    const int*   pool_idx   = (const int*)d_in[14];
    const int*   p2r_idx    = (const int*)d_in[15];
    const int*   r2p_idx    = (const int*)d_in[16];
    float* out = (float*)d_out;

    char* ws = (char*)d_ws;
    ushort* wB   = (ushort*)ws; ws += 24576 * 2;                   // 48 KB
    ushort* pfT  = (ushort*)ws; ws += (size_t)BB * NPTS * CC * 2;  // 13.1 MB
    ushort* rgbT = (ushort*)ws; ws += (size_t)BB * HWN  * CC * 2;  // 19.7 MB
    ushort* pe0T = (ushort*)ws; ws += (size_t)BB * NSUB * CC * 2;  // 3.3 MB
    ushort* p2rT = (ushort*)ws; ws += (size_t)BB * NSUB * CC * 2;
    ushort* r2pT = (ushort*)ws; ws += (size_t)BB * NSUB * CC * 2;

    k_prep<<<dim3(512, BB), 256, 0, stream>>>(pfeat, rgb, pfT, rgbT,
                                              w_p2r_pre, w_r2p_pre, w_p2r_fuse, w_r2p_fuse, wB);

    k_gather_pre<<<dim3(100, BB), 256, 0, stream>>>(pfT, rgbT, pool_idx, r2p_idx, wB,
                                                    s_p2r_pre, b_p2r_pre, s_r2p_pre, b_r2p_pre,
                                                    pe0T, p2rT, r2pT);

    k_fuse<<<dim3(350, BB), 256, 0, stream>>>(rgbT, p2rT, pe0T, r2pT, p2r_idx, wB,
                                              s_p2r_fuse, b_p2r_fuse, s_r2p_fuse, b_r2p_fuse, out);
}